// Round 1
// 405.323 us; speedup vs baseline: 1.0399x; 1.0399x over previous
//
#include <hip/hip_runtime.h>
#include <hip/hip_bf16.h>

// Problem constants
#define N_ATOM 2000
#define MNBR   12
#define OFEA   92
#define AF     64
#define BFEA   41
#define K1     169   // 2A+B
#define O1     128
#define OE     82
#define K3     274   // 3A+2B
#define NM     24000
#define NCONV  3
#define HID    128
#define NCRY   64
#define EPS_BN 1e-5f

#define LDA_T  192   // bf16 weight leading dim (169 padded to 192)
#define LDH    512   // REST: [h(0..127)|he(128..209)|pad|P'(256..383)|Q'(384..511)]
#define LDSW   88    // LDS row pitch (ushorts) for MFMA tiles
#define LDE    48    // padded E stride (41 -> 48, float4-aligned rows)

typedef __bf16 bf16x8 __attribute__((ext_vector_type(8)));
typedef float  f32x4  __attribute__((ext_vector_type(4)));

__device__ __forceinline__ float sigmoidf_(float x){
    return __builtin_amdgcn_rcpf(1.f + __expf(-x));
}
__device__ __forceinline__ float softplusf_(float x){
    return fmaxf(x,0.f) + __logf(1.f + __expf(-fabsf(x)));
}

__device__ __forceinline__ uint4 pack_bf16_8(const float* v){
    __hip_bfloat16 o[8];
    #pragma unroll
    for (int j=0;j<8;j++) o[j] = __float2bfloat16(v[j]);
    return *(const uint4*)o;
}

// ================= bf16 MFMA GEMM with fused gather (A-tile from X/E48/idx)
// and fused BN statistics in the epilogue.
// STL layout (floats): S1A[0..255] S2A[256..511] S13[512..639] S23[640..767]
//                      S12[768..831] S22[832..895] S2P[896..1023] S2Q[1024..1151]
__global__ __launch_bounds__(256, 3)
void gemm_fused(const float* __restrict__ X,
                const float* __restrict__ E48,
                const int*   __restrict__ idx,
                const __hip_bfloat16* __restrict__ W,
                const float* __restrict__ bias,
                float* __restrict__ REST,
                float* __restrict__ STL,
                float* __restrict__ SPA,
                float* __restrict__ SQA)
{
    __shared__ unsigned short As[128][LDSW];
    __shared__ unsigned short Ws[128][LDSW];
    __shared__ float cs1[128];
    __shared__ float cs2[128];
    __shared__ float spa[12][128];   // per-atom P'/Q' row-sums (block spans <=12 atoms)

    const int tid  = threadIdx.x;
    const int row0 = blockIdx.x * 128;
    const int col0 = blockIdx.y * 128;
    const int w    = tid >> 6;
    const int l    = tid & 63;
    const int wm   = w >> 1, wn = w & 1;
    const int lrow = l & 15;
    const int quad = l >> 4;

    // zero stats LDS (visible after first __syncthreads below)
    if (tid < 128){ cs1[tid] = 0.f; cs2[tid] = 0.f; }
    for (int ii = tid; ii < 12*128; ii += 256) spa[ii>>7][ii&127] = 0.f;

    f32x4 acc[4][4];
    #pragma unroll
    for (int i=0;i<4;i++)
        #pragma unroll
        for (int j=0;j<4;j++) acc[i][j] = (f32x4){0.f,0.f,0.f,0.f};

    #pragma unroll
    for (int it = 0; it < 3; ++it){
        const int k0 = it * 64;
        if (it) __syncthreads();
        #pragma unroll
        for (int j = 0; j < 4; ++j){
            int e  = tid + j*256;
            int r  = e >> 3;
            int kk = (e & 7) << 3;
            int grow = row0 + r;
            // ---- A tile: gather + convert (TOT cols: [x | xn | e48pad])
            float v[8];
            #pragma unroll
            for (int q2=0;q2<8;q2++) v[q2] = 0.f;
            if (grow < NM){
                if (it == 2){
                    if (kk < LDE){
                        const float* s = E48 + (size_t)grow*LDE + kk;
                        float4 a0 = *(const float4*)s;
                        float4 a1 = *(const float4*)(s+4);
                        v[0]=a0.x; v[1]=a0.y; v[2]=a0.z; v[3]=a0.w;
                        v[4]=a1.x; v[5]=a1.y; v[6]=a1.z; v[7]=a1.w;
                    }
                } else {
                    const float* s = (it == 0)
                        ? X + (size_t)((unsigned)grow/12u)*AF + kk
                        : X + (size_t)idx[grow]*AF + kk;
                    float4 a0 = *(const float4*)s;
                    float4 a1 = *(const float4*)(s+4);
                    v[0]=a0.x; v[1]=a0.y; v[2]=a0.z; v[3]=a0.w;
                    v[4]=a1.x; v[5]=a1.y; v[6]=a1.z; v[7]=a1.w;
                }
            }
            *(uint4*)(&As[r][kk]) = pack_bf16_8(v);
            // ---- W tile (pre-packed bf16)
            uint4 vw = *(const uint4*)(W + (size_t)(col0 + r)*LDA_T + k0 + kk);
            *(uint4*)(&Ws[r][kk]) = vw;
        }
        __syncthreads();
        #pragma unroll
        for (int ks = 0; ks < 2; ++ks){
            int koff = ks*32 + quad*8;
            bf16x8 a_[4], b_[4];
            #pragma unroll
            for (int mi=0;mi<4;mi++)
                a_[mi] = *(const bf16x8*)(&As[wm*64 + mi*16 + lrow][koff]);
            #pragma unroll
            for (int ni=0;ni<4;ni++)
                b_[ni] = *(const bf16x8*)(&Ws[wn*64 + ni*16 + lrow][koff]);
            #pragma unroll
            for (int mi=0;mi<4;mi++)
                #pragma unroll
                for (int ni=0;ni<4;ni++)
                    acc[mi][ni] = __builtin_amdgcn_mfma_f32_16x16x32_bf16(
                        a_[mi], b_[ni], acc[mi][ni], 0, 0, 0);
        }
    }

    // ---------------- epilogue: store + fused BN stats ----------------
    const bool isPQ = (col0 >= 256);
    const int atomBase = (unsigned)row0 / 12u;
    int rbase_[4], n0_[4], sp_[4];
    #pragma unroll
    for (int mi=0;mi<4;mi++){
        rbase_[mi] = row0 + wm*64 + mi*16 + quad*4;
        int n0 = (int)((unsigned)rbase_[mi] / 12u);
        n0_[mi] = n0;
        sp_[mi] = 12 - (rbase_[mi] - n0*12);   // reg index where the next atom starts
    }

    #pragma unroll
    for (int ni=0;ni<4;ni++){
        const int cl  = wn*64 + ni*16 + lrow;   // 0..127 within block
        const int col = col0 + cl;
        const float bv = bias[col];
        float s1 = 0.f, s2 = 0.f;
        #pragma unroll
        for (int mi=0;mi<4;mi++){
            const int rbase = rbase_[mi];
            float run0 = 0.f, run1 = 0.f;
            #pragma unroll
            for (int reg=0;reg<4;reg++){
                int grow = rbase + reg;
                if (grow < NM){
                    float vv = acc[mi][ni][reg] + bv;
                    if (col0 != 128 || col < 210)     // cols 210..255 are dead padding
                        REST[(size_t)grow*LDH + col] = vv;
                    s1 += vv; s2 += vv*vv;
                    if (isPQ){
                        if (reg < sp_[mi]) run0 += vv; else run1 += vv;
                    }
                }
            }
            if (isPQ){
                if (run0 != 0.f) atomicAdd(&spa[n0_[mi]     - atomBase][cl], run0);
                if (run1 != 0.f) atomicAdd(&spa[n0_[mi] + 1 - atomBase][cl], run1);
            }
        }
        if (isPQ){
            atomicAdd(&cs2[cl], s2);
        } else {
            atomicAdd(&cs1[cl], s1);
            atomicAdd(&cs2[cl], s2);
        }
    }
    __syncthreads();
    if (!isPQ){
        if (tid < 128){
            atomicAdd(&STL[col0 + tid],       cs1[tid]);   // S1A
            atomicAdd(&STL[256 + col0 + tid], cs2[tid]);   // S2A
        }
    } else {
        if (tid < 128)
            atomicAdd(&STL[(col0 == 256 ? 896 : 1024) + tid], cs2[tid]); // S2P / S2Q
        float* SPQd = (col0 == 256) ? SPA : SQA;
        for (int ii = tid; ii < 12*128; ii += 256){
            int ai = ii >> 7, c2 = ii & 127;
            int na = atomBase + ai;
            float val = spa[ai][c2];
            if (val != 0.f && na < N_ATOM)
                atomicAdd(&SPQd[(size_t)na*128 + c2], val);
        }
    }
}

// ================= fold per-atom P/Q sums into closed-form BN3 sums
__global__ __launch_bounds__(256)
void bn3_pre(const float* __restrict__ SPA, const float* __restrict__ SQA,
             float* __restrict__ STL)
{
    const int c    = threadIdx.x & 127;
    const int half = threadIdx.x >> 7;
    float s1 = 0.f, sx = 0.f;
    for (int n = blockIdx.x*2 + half; n < N_ATOM; n += 64){
        float p = SPA[(size_t)n*128 + c];
        float q = SQA[(size_t)n*128 + c];
        s1 += p + q;
        sx += p * q;
    }
    atomicAdd(&STL[512 + c], 12.f*s1);   // S13
    atomicAdd(&STL[640 + c], 2.f*sx);    // S23 (cross term; 12*(spp+sqq) added in bn_fin)
}

// ================= small fp32 GEMM (embedding / head)
#define BM 64
#define BN 128
#define BK 32
template<int EPI, int SPIN>
__global__ __launch_bounds__(256)
void gemm_tn(const float* __restrict__ T, int ldt, int R,
             const float* __restrict__ W, int ldw, int K, int O,
             const float* __restrict__ bias,
             float* __restrict__ C, int ldc)
{
    __shared__ float Ts[BM][BK+1];
    __shared__ float Ws2[BN][BK+1];
    const int tid = threadIdx.x;
    const int row0 = blockIdx.x * BM;
    const int tx = tid % 16;
    const int ty = tid / 16;
    float acc[4][8];
    #pragma unroll
    for (int i=0;i<4;i++)
        #pragma unroll
        for (int j=0;j<8;j++) acc[i][j]=0.f;

    for (int k0 = 0; k0 < K; k0 += BK) {
        #pragma unroll
        for (int i=0;i<(BM*BK)/256;i++){
            int e = tid + i*256;
            int r = e / BK, k = e % BK;
            int gr = row0 + r, gk = k0 + k;
            float v = 0.f;
            if (gr < R && gk < K){
                v = T[(size_t)gr*ldt + gk];
                if (SPIN) v = softplusf_(v);
            }
            Ts[r][k] = v;
        }
        #pragma unroll
        for (int i=0;i<(BN*BK)/256;i++){
            int e = tid + i*256;
            int r = e / BK, k = e % BK;
            int gk = k0 + k;
            Ws2[r][k] = (r < O && gk < K) ? W[(size_t)r*ldw + gk] : 0.f;
        }
        __syncthreads();
        #pragma unroll
        for (int k=0;k<BK;k++){
            float a_[4], b_[8];
            #pragma unroll
            for (int i=0;i<4;i++) a_[i] = Ts[ty*4+i][k];
            #pragma unroll
            for (int j=0;j<8;j++) b_[j] = Ws2[tx + j*16][k];
            #pragma unroll
            for (int i=0;i<4;i++)
                #pragma unroll
                for (int j=0;j<8;j++)
                    acc[i][j] += a_[i]*b_[j];
        }
        __syncthreads();
    }
    #pragma unroll
    for (int i=0;i<4;i++){
        int gr = row0 + ty*4 + i;
        if (gr >= R) continue;
        #pragma unroll
        for (int j=0;j<8;j++){
            int gc = tx + j*16;
            if (gc >= O) continue;
            float v = acc[i][j] + (bias ? bias[gc] : 0.f);
            if (EPI==1) v = softplusf_(v);
            C[(size_t)gr*ldc + gc] = v;
        }
    }
}

// ================= pack weights (bf16) + bias (fp32).
__global__ void pack_all(const float* __restrict__ fcW, const float* __restrict__ eW,
                         const float* __restrict__ W3, const float* __restrict__ fcb,
                         const float* __restrict__ eb, const float* __restrict__ b3,
                         __hip_bfloat16* __restrict__ WALL, float* __restrict__ BIAS)
{
    int i = blockIdx.x*blockDim.x + threadIdx.x;
    const int nW = NCONV*512*LDA_T;
    if (i < nW){
        int l = i/(512*LDA_T), rem = i%(512*LDA_T);
        int c = rem/LDA_T, k = rem%LDA_T;
        float v = 0.f;
        if (c < O1){
            if (k < K1) v = fcW[((size_t)l*O1 + c)*K1 + k];
        } else if (c < O1+OE){
            if (k < K1) v = eW[((size_t)l*OE + (c-O1))*K1 + k];
        } else if (c >= 256 && c < 384){
            int o = c - 256;
            const float* W3l = W3 + (size_t)l*O1*K3;
            if (k < AF)                        v = 0.5f * W3l[(size_t)o*K3 + k];          // Wa/2
            else if (k < 2*AF)                 v = W3l[(size_t)o*K3 + k];                 // Wj
            else if (k < K1)                   v = W3l[(size_t)o*K3 + 192 + (k-128)];     // Wij
        } else if (c >= 384){
            int o = c - 384;
            const float* W3l = W3 + (size_t)l*O1*K3;
            if (k < AF)                        v = 0.5f * W3l[(size_t)o*K3 + k];          // Wa/2
            else if (k < 2*AF)                 v = W3l[(size_t)o*K3 + k + AF];            // Wl
            else if (k < K1)                   v = W3l[(size_t)o*K3 + 233 + (k-128)];     // Wil
        }
        WALL[i] = __float2bfloat16(v);
    } else if (i < nW + NCONV*512){
        int m = i - nW;
        int l = m/512, c = m%512;
        float v = 0.f;
        if (c < O1)         v = fcb[l*O1 + c];
        else if (c < O1+OE) v = eb[l*OE + (c-O1)];
        else if (c >= 256)  v = 0.5f * b3[l*O1 + ((c-256)&127)];
        BIAS[m] = v;
    }
}

// ================= nbr_fea [NM][41] -> E48 [NM][48] (zero-padded)
__global__ void e_init(const float* __restrict__ nbr, float* __restrict__ E48)
{
    int i = blockIdx.x*blockDim.x + threadIdx.x;
    if (i >= NM*LDE) return;
    int r = i / LDE, k = i % LDE;
    E48[i] = (k < BFEA) ? nbr[(size_t)r*BFEA + k] : 0.f;
}

// ================= BN finalize for all channels -> packed SC table
// SC[0..209]=sA, SC[256..465]=tA, SC[512..639]=s3, SC[640..767]=t3
__global__ void bn_fin_all(const float* __restrict__ STL,
                           const float* __restrict__ g1, const float* __restrict__ b1,
                           const float* __restrict__ ge, const float* __restrict__ be,
                           const float* __restrict__ g3, const float* __restrict__ b3b,
                           float* __restrict__ SC)
{
    int c = threadIdx.x;   // 256
    const float* S1A = STL;
    const float* S2A = STL + 256;
    const float* S13 = STL + 512;
    const float* S23 = STL + 640;
    const float* S2P = STL + 896;
    const float* S2Q = STL + 1024;
    if (c < O1+OE){
        float mean = S1A[c]*(1.f/NM);
        float var  = fmaxf(S2A[c]*(1.f/NM) - mean*mean, 0.f);
        float gg = (c < O1) ? g1[c] : ge[c-O1];
        float bb = (c < O1) ? b1[c] : be[c-O1];
        float sc = gg * rsqrtf(var + EPS_BN);
        SC[c] = sc; SC[256+c] = bb - sc*mean;
    }
    if (c < O1){
        float inv  = 1.f/((float)NM*MNBR);
        float mean = S13[c]*inv;
        float ex2  = (S23[c] + 12.f*(S2P[c] + S2Q[c]))*inv;
        float var  = fmaxf(ex2 - mean*mean, 0.f);
        float sc = g3[c] * rsqrtf(var + EPS_BN);
        SC[512+c] = sc; SC[640+c] = b3b[c] - sc*mean;
    }
}

// ================= consumer: block = atom, 128 threads (2 waves x 6 m's each).
__global__ __launch_bounds__(128)
void consumer_k(const float* __restrict__ REST, const float* __restrict__ SC,
                float* __restrict__ TB, float* __restrict__ E48)
{
    __shared__ float red[128];
    const int n = blockIdx.x;
    const int t = threadIdx.x;
    const int a = t & 63;
    const int g = t >> 6;     // 0..1
    const float* base = REST + (size_t)n*MNBR*LDH;

    float sha = SC[a],      tha = SC[256+a];
    float shb = SC[64+a],   thb = SC[256+64+a];
    float s3lo = SC[512+a], s3hi = SC[512+64+a];
    float t3lo = SC[640+a], t3hi = SC[640+64+a];

    float Qa[MNBR], Qb[MNBR];
    #pragma unroll
    for (int m=0;m<MNBR;m++){
        const float* row = base + (size_t)m*LDH;
        Qa[m] = s3lo*row[384+a];
        Qb[m] = s3hi*row[448+a];
    }
    float acc = 0.f;
    #pragma unroll
    for (int j=0;j<6;j++){
        const float* row = base + (size_t)(g*6+j)*LDH;
        acc += sigmoidf_(sha*row[a]+tha) * softplusf_(shb*row[64+a]+thb);
        float ua = s3lo*row[256+a] + t3lo;
        float ub = s3hi*row[320+a] + t3hi;
        #pragma unroll
        for (int l2=0;l2<MNBR;l2++)
            acc += sigmoidf_(ua + Qa[l2]) * softplusf_(ub + Qb[l2]);
    }
    red[t] = acc;
    __syncthreads();
    if (g == 0)
        TB[(size_t)n*AF + a] = red[a] + red[64+a];
    // edge update on padded E48; pads (cols 41..47) never touched
    for (int idx = t; idx < MNBR*BFEA; idx += 128){
        int m = idx / BFEA, b = idx % BFEA;
        const float* row = base + (size_t)m*LDH;
        float u = SC[O1+b]*row[O1+b]   + SC[256+O1+b];
        float v = SC[169+b]*row[169+b] + SC[256+169+b];
        E48[((size_t)n*MNBR + m)*LDE + b] += sigmoidf_(u) * softplusf_(v);
    }
}

// ================= per-column sum/sumsq for TB
__global__ __launch_bounds__(64)
void tb_stats_k(const float* __restrict__ TB,
                float* __restrict__ S1, float* __restrict__ S2)
{
    int t = threadIdx.x;
    float s1 = 0.f, s2 = 0.f;
    for (int r = blockIdx.x; r < N_ATOM; r += gridDim.x){
        float v = TB[(size_t)r*AF + t];
        s1 += v; s2 += v*v;
    }
    atomicAdd(&S1[t], s1);
    atomicAdd(&S2[t], s2);
}

// ================= x = softplus(x + bn2(TB)), inline finalize
__global__ void x_update_k(float* __restrict__ X, const float* __restrict__ TB,
                           const float* __restrict__ S12, const float* __restrict__ S22,
                           const float* __restrict__ g2, const float* __restrict__ b2,
                           int total)
{
    int i = blockIdx.x*blockDim.x + threadIdx.x;
    if (i >= total) return;
    int a = i & (AF-1);
    float mean = S12[a]*(1.f/N_ATOM);
    float var  = fmaxf(S22[a]*(1.f/N_ATOM) - mean*mean, 0.f);
    float sc = g2[a]*rsqrtf(var + EPS_BN);
    X[i] = softplusf_(X[i] + sc*TB[i] + (b2[a] - sc*mean));
}

// ================= pooled mean per crystal + final dot
__global__ __launch_bounds__(128)
void pool_out_k(const float* __restrict__ Z, const int* __restrict__ seg,
                const float* __restrict__ outW, const float* __restrict__ outb,
                float* __restrict__ out)
{
    __shared__ float red[128];
    const int c = blockIdx.x;
    const int h = threadIdx.x;
    int l0, l1;
    {
        int l=0, r=N_ATOM;
        while (l<r){ int m=(l+r)>>1; if (seg[m] < c) l=m+1; else r=m; }
        l0 = l;
        l=l0; r=N_ATOM;
        while (l<r){ int m=(l+r)>>1; if (seg[m] < c+1) l=m+1; else r=m; }
        l1 = l;
    }
    float s = 0.f;
    for (int n = l0; n < l1; ++n) s += Z[(size_t)n*HID + h];
    float cnt = fmaxf((float)(l1-l0), 1.f);
    red[h] = (s/cnt) * outW[h];
    __syncthreads();
    for (int off=64; off>0; off>>=1){
        if (h < off) red[h] += red[h+off];
        __syncthreads();
    }
    if (h == 0) out[c] = red[0] + outb[0];
}

extern "C" void kernel_launch(void* const* d_in, const int* in_sizes, int n_in,
                              void* d_out, int out_size, void* d_ws, size_t ws_size,
                              hipStream_t stream)
{
    const float* atom_fea = (const float*)d_in[0];
    const float* nbr_fea  = (const float*)d_in[1];
    const int*   nbr_idx  = (const int*)d_in[2];
    const int*   site_seg = (const int*)d_in[3];
    const float* emb_W = (const float*)d_in[4];
    const float* emb_b = (const float*)d_in[5];
    const float* fcW   = (const float*)d_in[6];
    const float* fcb   = (const float*)d_in[7];
    const float* bn1_g = (const float*)d_in[8];
    const float* bn1_b = (const float*)d_in[9];
    const float* bn2_g = (const float*)d_in[10];
    const float* bn2_b = (const float*)d_in[11];
    const float* eW    = (const float*)d_in[12];
    const float* eb    = (const float*)d_in[13];
    const float* bne_g = (const float*)d_in[14];
    const float* bne_b = (const float*)d_in[15];
    const float* W3    = (const float*)d_in[16];
    const float* b3    = (const float*)d_in[17];
    const float* bn3_g = (const float*)d_in[18];
    const float* bn3_b = (const float*)d_in[19];
    const float* fc1W  = (const float*)d_in[20];
    const float* fc1b  = (const float*)d_in[21];
    const float* outW  = (const float*)d_in[22];
    const float* outb  = (const float*)d_in[23];

    // workspace layout (float units)
    float* ws   = (float*)d_ws;
    float* X    = ws;                         // 128,000
    float* E48  = ws + 128000;                // 24000*48 = 1,152,000
    float* REST = ws + 1280000;               // 24000*512 = 12,288,000
    float* TB   = ws + 13568000;              // 128,000
    float* Z    = ws + 13696000;              // 256,000
    float* ST   = ws + 13952000;              // 3*2048 = 6,144
    float* SC   = ws + 13958144;              // 1,024
    float* SPQ  = ws + 13959168;              // 3 * 2 * 256,000 = 1,536,000
    __hip_bfloat16* WALL = (__hip_bfloat16*)(ws + 15495168); // 3*512*192 bf16
    float* BIAS = ws + 15642624;              // 1,536

    {
        int tot = NCONV*512*LDA_T + NCONV*512;
        pack_all<<<(tot+255)/256, 256, 0, stream>>>(fcW, eW, W3, fcb, eb, b3, WALL, BIAS);
    }
    // zero ST + SC + all per-layer SPA/SQA in one contiguous fill
    hipMemsetAsync(ST, 0, (size_t)(6144 + 1024 + 1536000) * sizeof(float), stream);
    gemm_tn<0,0><<<(N_ATOM+BM-1)/BM, 256, 0, stream>>>(atom_fea, OFEA, N_ATOM,
                                                       emb_W, OFEA, OFEA, AF, emb_b, X, AF);
    e_init<<<(NM*LDE+255)/256, 256, 0, stream>>>(nbr_fea, E48);

    for (int i = 0; i < NCONV; i++){
        const float* g1 = bn1_g + i*O1, *b1 = bn1_b + i*O1;
        const float* g2 = bn2_g + i*AF, *b2 = bn2_b + i*AF;
        const float* ge = bne_g + i*OE, *be = bne_b + i*OE;
        const float* g3 = bn3_g + i*O1, *b3b = bn3_b + i*O1;
        float* STL = ST + i*2048;
        float* SPA = SPQ + (size_t)i*512000;
        float* SQA = SPA + 256000;
        float *S12 = STL+768, *S22 = STL+832;

        {
            dim3 g((NM+127)/128, 4);
            gemm_fused<<<g, 256, 0, stream>>>(X, E48, nbr_idx,
                                              WALL + (size_t)i*512*LDA_T,
                                              BIAS + i*512, REST, STL, SPA, SQA);
        }
        bn3_pre<<<32, 256, 0, stream>>>(SPA, SQA, STL);
        bn_fin_all<<<1, 256, 0, stream>>>(STL, g1, b1, ge, be, g3, b3b, SC);
        consumer_k<<<N_ATOM, 128, 0, stream>>>(REST, SC, TB, E48);
        tb_stats_k<<<128, 64, 0, stream>>>(TB, S12, S22);
        x_update_k<<<(N_ATOM*AF+255)/256, 256, 0, stream>>>(X, TB, S12, S22, g2, b2,
                                                            N_ATOM*AF);
    }

    // head: Z = softplus(softplus(X) @ fc1W^T + fc1b); pooled mean; out
    gemm_tn<1,1><<<(N_ATOM+BM-1)/BM, 256, 0, stream>>>(X, AF, N_ATOM, fc1W, AF, AF, HID,
                                                       fc1b, Z, HID);
    pool_out_k<<<NCRY, 128, 0, stream>>>(Z, site_seg, outW, outb, (float*)d_out);
}